// Round 3
// baseline (131.022 us; speedup 1.0000x reference)
//
#include <hip/hip_runtime.h>
#include <hip/hip_bf16.h>

#define NH   32
#define NKVH 8
#define NG   4
#define DD   128
#define HID  4096
#define NQKV 6144
#define NB   32
#define SS   2048
#define SCALE 0.08838834764831845f
#define CHUNK 128
#define NCHUNK 16

typedef __attribute__((ext_vector_type(4))) float f32x4;
typedef __attribute__((ext_vector_type(8))) short bf16x8;
typedef __attribute__((ext_vector_type(4))) unsigned int u32x4;

static __device__ __forceinline__ unsigned short f2bf(float f) {
    __hip_bfloat16 h = __float2bfloat16(f);
    return __builtin_bit_cast(unsigned short, h);
}

// pack two f32 -> {bf16(a) low, bf16(b) high} with half-ULP bias rounding:
// 2 v_add_u32 + 1 v_perm_b32
static __device__ __forceinline__ unsigned int pack_bf16(float a, float b) {
    unsigned int ua = __builtin_bit_cast(unsigned int, a) + 0x8000u;
    unsigned int ub = __builtin_bit_cast(unsigned int, b) + 0x8000u;
    return __builtin_amdgcn_perm(ub, ua, 0x07060302u);
}

// ---------------- convert hidden_states to bf16 ----------------
__global__ void cvt_hs(const float* __restrict__ in, unsigned short* __restrict__ out) {
    int i = blockIdx.x * 256 + threadIdx.x;   // 131072 total
    out[i] = f2bf(in[i]);
}

// ---------------- skinny GEMM with grid split-K ----------------
// Part[ks][32][N] = Abf[32][Kslice] * W[N][Kslice]^T for K-slice ks.
// grid = (N/16, SPLIT); block = 256 (4 waves), wave splits slice /4.
template<int SPLIT>
__global__ __launch_bounds__(256) void gemm32_s(
    const unsigned short* __restrict__ Abf,
    const float* __restrict__ W,
    float* __restrict__ Part,
    int K, int N) {
    int j0 = blockIdx.x * 16;
    int ks = blockIdx.y;
    int tid = threadIdx.x;
    int wave = tid >> 6;
    int lane = tid & 63;
    int l16 = lane & 15;
    int kgrp = lane >> 4;
    int Kslice = K / SPLIT;
    int Kq = Kslice >> 2;
    int kbeg = ks * Kslice + wave * Kq;
    int kend = kbeg + Kq;

    f32x4 acc0 = {0.f, 0.f, 0.f, 0.f};
    f32x4 acc1 = {0.f, 0.f, 0.f, 0.f};
    const unsigned short* arow0 = Abf + (size_t)l16 * K;
    const unsigned short* arow1 = Abf + (size_t)(16 + l16) * K;
    const float* wrow = W + (size_t)(j0 + l16) * K;

#pragma unroll 4
    for (int k = kbeg; k < kend; k += 32) {
        int kk = k + kgrp * 8;
        bf16x8 a0 = *(const bf16x8*)(arow0 + kk);
        bf16x8 a1 = *(const bf16x8*)(arow1 + kk);
        f32x4 w0 = *(const f32x4*)(wrow + kk);
        f32x4 w1 = *(const f32x4*)(wrow + kk + 4);
        u32x4 pk;
        pk[0] = pack_bf16(w0[0], w0[1]);
        pk[1] = pack_bf16(w0[2], w0[3]);
        pk[2] = pack_bf16(w1[0], w1[1]);
        pk[3] = pack_bf16(w1[2], w1[3]);
        bf16x8 bw = __builtin_bit_cast(bf16x8, pk);
        acc0 = __builtin_amdgcn_mfma_f32_16x16x32_bf16(a0, bw, acc0, 0, 0, 0);
        acc1 = __builtin_amdgcn_mfma_f32_16x16x32_bf16(a1, bw, acc1, 0, 0, 0);
    }

    __shared__ f32x4 red[4][2][64];
    red[wave][0][lane] = acc0;
    red[wave][1][lane] = acc1;
    __syncthreads();
    if (wave == 0) {
        for (int t = 0; t < 2; ++t) {
            f32x4 s = red[0][t][lane];
            s += red[1][t][lane];
            s += red[2][t][lane];
            s += red[3][t][lane];
            for (int r = 0; r < 4; ++r)
                Part[((size_t)ks * 32 + t * 16 + kgrp * 4 + r) * N + j0 + l16] = s[r];
        }
    }
}

// ---------------- attention partial (flash-decode, split-S), fused rope ----------------
// qkv_part: [4][32][NQKV] split-K partials of the qkv GEMM.
// grid: (B*KVH, NCHUNK), block 256. part stride per (bk,c): 520 f32 = {m[4], l[4], acc[4][128]}
__global__ __launch_bounds__(256) void attn_partial(
    const float* __restrict__ k_cache, const float* __restrict__ v_cache,
    const float* __restrict__ qkv_part, const int* __restrict__ positions,
    float* __restrict__ part) {
    int bk = blockIdx.x;
    int c = blockIdx.y;
    int b = bk >> 3, kvh = bk & 7;
    int pos = positions[b];
    int s0 = c * CHUNK;
    float* mypart = part + ((size_t)bk * NCHUNK + c) * 520;
    int tid = threadIdx.x;
    if (s0 > pos) {
        if (tid < 4) { mypart[tid] = -__builtin_inff(); mypart[4 + tid] = 0.f; }
        return;
    }
    int nvalid = min(pos + 1 - s0, CHUNK);

    // raw[0..511] = q (4 heads), [512..639] = k, [640..767] = v
    __shared__ __attribute__((aligned(16))) float raw[768];
    __shared__ float cs0[64], sn0[64];
    __shared__ float sc[4][CHUNK];
    __shared__ float mg[4], lg[4];
    __shared__ f32x4 red[8][4][32];

    for (int i = tid; i < 4 * CHUNK; i += 256) ((float*)sc)[i] = -__builtin_inff();
    if (tid < 64) {
        float inv = exp2f(-(float)tid * 0.20762050593046f);   // theta^(-i/64)
        float f = (float)pos * inv;
        sincosf(f, &sn0[tid], &cs0[tid]);
    }
    // sum the 4 split-K partials for this block's heads
    for (int idx = tid; idx < 768; idx += 256) {
        int col;
        if (idx < 512)      col = (kvh * NG) * DD + idx;
        else if (idx < 640) col = (NH + kvh) * DD + (idx - 512);
        else                col = (NH + NKVH + kvh) * DD + (idx - 640);
        size_t base = (size_t)b * NQKV + col;
        raw[idx] = qkv_part[base]
                 + qkv_part[base + (size_t)32 * NQKV]
                 + qkv_part[base + (size_t)64 * NQKV]
                 + qkv_part[base + (size_t)96 * NQKV];
    }
    __syncthreads();
    // rope in place: 5 heads (4 q + 1 k) x 64 pairs
    for (int idx = tid; idx < 320; idx += 256) {
        int h = idx >> 6, i = idx & 63;
        int off = h * 128;
        float x1 = raw[off + i], x2 = raw[off + i + 64];
        float c0 = cs0[i], s1 = sn0[i];
        raw[off + i] = x1 * c0 - x2 * s1;
        raw[off + i + 64] = x2 * c0 + x1 * s1;
    }
    __syncthreads();

    int wave = tid >> 6, lane = tid & 63, l16 = lane & 15, rsub = lane >> 4;

    // q fragments: qf[g][e], d = l16*8+e
    float qf[4][8];
#pragma unroll
    for (int g = 0; g < 4; ++g)
#pragma unroll
        for (int e = 0; e < 8; ++e)
            qf[g][e] = raw[g * DD + l16 * 8 + e];

    // scores
    for (int it = 0; it < CHUNK / 16; ++it) {
        int row = it * 16 + wave * 4 + rsub;
        if (row >= nvalid) continue;
        int s = s0 + row;
        f32x4 k0, k1;
        if (s == pos) {
            k0 = *(const f32x4*)(&raw[512 + l16 * 8]);
            k1 = *(const f32x4*)(&raw[512 + l16 * 8 + 4]);
        } else {
            const float* krow = k_cache + (((size_t)b * SS + s) * NKVH + kvh) * DD;
            k0 = *(const f32x4*)(krow + l16 * 8);
            k1 = *(const f32x4*)(krow + l16 * 8 + 4);
        }
        float dots[4];
#pragma unroll
        for (int g = 0; g < 4; ++g) {
            dots[g] = qf[g][0] * k0[0] + qf[g][1] * k0[1] + qf[g][2] * k0[2] + qf[g][3] * k0[3]
                    + qf[g][4] * k1[0] + qf[g][5] * k1[1] + qf[g][6] * k1[2] + qf[g][7] * k1[3];
        }
#pragma unroll
        for (int m = 1; m < 16; m <<= 1)
#pragma unroll
            for (int g = 0; g < 4; ++g)
                dots[g] += __shfl_xor(dots[g], m, 64);
        if (l16 == 0)
#pragma unroll
            for (int g = 0; g < 4; ++g) sc[g][row] = dots[g] * SCALE;
    }
    __syncthreads();

    // softmax partial: wave g handles row-group g (CHUNK=128 -> 2 vals/lane)
    {
        int g = wave;
        float v0 = sc[g][lane], v1 = sc[g][lane + 64];
        float m = fmaxf(v0, v1);
#pragma unroll
        for (int msk = 1; msk < 64; msk <<= 1) m = fmaxf(m, __shfl_xor(m, msk, 64));
        float p0 = expf(v0 - m), p1 = expf(v1 - m);
        float l = p0 + p1;
#pragma unroll
        for (int msk = 1; msk < 64; msk <<= 1) l += __shfl_xor(l, msk, 64);
        sc[g][lane] = p0; sc[g][lane + 64] = p1;
        if (lane == 0) { mg[g] = m; lg[g] = l; }
    }
    __syncthreads();

    // PV: thread (sid = tid>>5 s-split, l32 = tid&31 d-chunk), 4 g's per thread
    int sid = tid >> 5, l32 = tid & 31;
    f32x4 acc[4] = {{0.f,0.f,0.f,0.f},{0.f,0.f,0.f,0.f},{0.f,0.f,0.f,0.f},{0.f,0.f,0.f,0.f}};
    for (int row = sid; row < nvalid; row += 8) {
        int s = s0 + row;
        f32x4 v4;
        if (s == pos) {
            v4 = *(const f32x4*)(&raw[640 + l32 * 4]);
        } else {
            const float* vrow = v_cache + (((size_t)b * SS + s) * NKVH + kvh) * DD;
            v4 = *(const f32x4*)(vrow + l32 * 4);
        }
#pragma unroll
        for (int g = 0; g < 4; ++g)
            acc[g] += sc[g][row] * v4;
    }
#pragma unroll
    for (int g = 0; g < 4; ++g) red[sid][g][l32] = acc[g];
    __syncthreads();

    if (tid < 128) {
        int g = tid >> 5, l = tid & 31;
        f32x4 s = red[0][g][l];
#pragma unroll
        for (int w = 1; w < 8; ++w) s += red[w][g][l];
        *(f32x4*)(mypart + 8 + g * DD + l * 4) = s;
        if (l == 0) { mypart[g] = mg[g]; mypart[4 + g] = lg[g]; }
    }
}

// ---------------- combine partials -> attn activations (bf16) ----------------
__global__ __launch_bounds__(128) void attn_combine(
    const float* __restrict__ part, unsigned short* __restrict__ attn_bf) {
    int bk = blockIdx.x;
    int b = bk >> 3, kvh = bk & 7;
    const float* p0 = part + (size_t)bk * NCHUNK * 520;
    int tid = threadIdx.x;
    int g = tid >> 5, l32 = tid & 31;

    float M = -__builtin_inff();
#pragma unroll
    for (int c = 0; c < NCHUNK; ++c) {
        float lcv = p0[c * 520 + 4 + g];
        float mcv = p0[c * 520 + g];
        if (lcv > 0.f && mcv > M) M = mcv;
    }
    float L = 0.f;
    f32x4 acc = {0.f, 0.f, 0.f, 0.f};
#pragma unroll
    for (int c = 0; c < NCHUNK; ++c) {
        float lcv = p0[c * 520 + 4 + g];
        float mcv = p0[c * 520 + g];
        if (lcv > 0.f) {
            float wgt = expf(mcv - M);
            L += lcv * wgt;
            f32x4 a = *(const f32x4*)(p0 + c * 520 + 8 + g * DD + l32 * 4);
            acc += wgt * a;
        }
    }
    float inv = 1.0f / L;
    unsigned short* o = attn_bf + (((size_t)b * NH) + kvh * NG + g) * DD + l32 * 4;
#pragma unroll
    for (int r = 0; r < 4; ++r) o[r] = f2bf(acc[r] * inv);
}

// ---------------- reduce o partials -> out ----------------
__global__ __launch_bounds__(256) void reduce_o(const float* __restrict__ part,
                                                float* __restrict__ out) {
    int idx = blockIdx.x * 256 + threadIdx.x;   // 32768 f32x4 groups
    const f32x4* p = (const f32x4*)part;
    f32x4 s = p[idx];
    s += p[idx + 32768];
    s += p[idx + 65536];
    s += p[idx + 98304];
    ((f32x4*)out)[idx] = s;
}

extern "C" void kernel_launch(void* const* d_in, const int* in_sizes, int n_in,
                              void* d_out, int out_size, void* d_ws, size_t ws_size,
                              hipStream_t stream) {
    const float* hs      = (const float*)d_in[0];
    const float* w_qkv   = (const float*)d_in[1];
    const float* w_o     = (const float*)d_in[2];
    const float* k_cache = (const float*)d_in[3];
    const float* v_cache = (const float*)d_in[4];
    const int*   positions = (const int*)d_in[5];
    float* out = (float*)d_out;

    char* ws = (char*)d_ws;
    unsigned short* hs_bf   = (unsigned short*)(ws);             // 262144 B
    float* qkv_part         = (float*)(ws + 262144);             // 3145728 B  [4][32][6144]
    float* part             = (float*)(ws + 3407872);            // 8519680 B
    unsigned short* attn_bf = (unsigned short*)(ws + 11927552);  // 262144 B
    float* o_part           = (float*)(ws + 12189696);           // 2097152 B  [4][32][4096]

    hipLaunchKernelGGL(cvt_hs, dim3(512), dim3(256), 0, stream, hs, hs_bf);
    hipLaunchKernelGGL((gemm32_s<4>), dim3(NQKV / 16, 4), dim3(256), 0, stream,
                       hs_bf, w_qkv, qkv_part, HID, NQKV);
    hipLaunchKernelGGL(attn_partial, dim3(NB * NKVH, NCHUNK), dim3(256), 0, stream,
                       k_cache, v_cache, qkv_part, positions, part);
    hipLaunchKernelGGL(attn_combine, dim3(NB * NKVH), dim3(128), 0, stream, part, attn_bf);
    hipLaunchKernelGGL((gemm32_s<4>), dim3(HID / 16, 4), dim3(256), 0, stream,
                       attn_bf, w_o, o_part, HID, HID);
    hipLaunchKernelGGL(reduce_o, dim3(128), dim3(256), 0, stream, o_part, out);
}